// Round 8
// baseline (225.335 us; speedup 1.0000x reference)
//
#include <hip/hip_runtime.h>

// GCNConv: out = A_hat @ x @ W + b, A_hat = D^-1/2 (A + I) D^-1/2
// v8: grid-fused scatter+GEMM (scatter-role blocks' latency hidden under
// GEMM-role blocks' MFMA compute; h = xW bf16 UNSCALED), per-bucket LDS
// counting sort -> sorted CSR + dinv, then one-wave-per-node gather with
// per-edge dinv[src] (wave-uniform broadcast load) and bias fused.

#define SCAN_T 256
#define SCAN_E 1024
#define WPB 4
#define CAP 1536      // bucket capacity (mean 1024, +16 sigma)
#define SC_T 4096     // edges per scatter-role block

typedef __attribute__((ext_vector_type(8))) short short8;
typedef __attribute__((ext_vector_type(4))) float f32x4;

__device__ __forceinline__ unsigned short f2bf(float f) {
  unsigned int u = __float_as_uint(f);
  u += 0x7FFFu + ((u >> 16) & 1u);   // RNE
  return (unsigned short)(u >> 16);
}
__device__ __forceinline__ float bf_lo(unsigned int u) { return __uint_as_float(u << 16); }
__device__ __forceinline__ float bf_hi(unsigned int u) { return __uint_as_float(u & 0xFFFF0000u); }

// ======================= v8 primary path =======================

__global__ void k_zero(int* __restrict__ p, int m) {
  int i = blockIdx.x * blockDim.x + threadIdx.x;
  if (i < m) p[i] = 0;
}

// Fused at grid level: blocks [0,SB) scatter edges into dst>>6 buckets;
// blocks [SB, SB+NB) compute h = x@W (bf16, NO dinv folding) for 64 rows.
// Scatter-role latency (LDS atomics, scattered stores) hides under the
// GEMM-role MFMA waves co-resident on each CU.
__global__ void __launch_bounds__(256) k_scatter_gemm(
    const int* __restrict__ ei, int* __restrict__ bcursor,
    int* __restrict__ pairs, int E, int B, int SB,
    const float* __restrict__ x, const float* __restrict__ W,
    unsigned short* __restrict__ h, int n) {
  __shared__ alignas(16) char smem[128 * 136 * 2];  // union: hist[2048] | Wt[128][136]
  int t = threadIdx.x;
  int bid = blockIdx.x;

  if (bid < SB) {
    // ---- scatter role: pairs[b*CAP + slot] = (dst&63)<<17 | src ----
    int* hist = (int*)smem;
    for (int b = t; b < B; b += 256) hist[b] = 0;
    __syncthreads();
    int e0 = bid * SC_T;
    int eend = min(e0 + SC_T, E);
    for (int e = e0 + t * 4; e < eend; e += 1024) {
      if (e + 3 < eend) {
        int4 d = *(const int4*)(ei + E + e);
        atomicAdd(&hist[((unsigned)d.x) >> 6], 1);
        atomicAdd(&hist[((unsigned)d.y) >> 6], 1);
        atomicAdd(&hist[((unsigned)d.z) >> 6], 1);
        atomicAdd(&hist[((unsigned)d.w) >> 6], 1);
      } else {
        for (int q = e; q < eend; ++q) atomicAdd(&hist[((unsigned)ei[E + q]) >> 6], 1);
      }
    }
    __syncthreads();
    for (int b = t; b < B; b += 256) {
      int c = hist[b];
      hist[b] = c ? atomicAdd(&bcursor[b], c) : 0;  // base within bucket
    }
    __syncthreads();
    for (int e = e0 + t * 4; e < eend; e += 1024) {
      if (e + 3 < eend) {
        int4 s = *(const int4*)(ei + e);
        int4 d = *(const int4*)(ei + E + e);
        int b0 = ((unsigned)d.x) >> 6; int p0 = atomicAdd(&hist[b0], 1);
        if (p0 < CAP) pairs[(size_t)b0 * CAP + p0] = ((d.x & 63) << 17) | s.x;
        int b1 = ((unsigned)d.y) >> 6; int p1 = atomicAdd(&hist[b1], 1);
        if (p1 < CAP) pairs[(size_t)b1 * CAP + p1] = ((d.y & 63) << 17) | s.y;
        int b2 = ((unsigned)d.z) >> 6; int p2 = atomicAdd(&hist[b2], 1);
        if (p2 < CAP) pairs[(size_t)b2 * CAP + p2] = ((d.z & 63) << 17) | s.z;
        int b3 = ((unsigned)d.w) >> 6; int p3 = atomicAdd(&hist[b3], 1);
        if (p3 < CAP) pairs[(size_t)b3 * CAP + p3] = ((d.w & 63) << 17) | s.w;
      } else {
        for (int q = e; q < eend; ++q) {
          int dst = ei[E + q], src = ei[q];
          int b0 = ((unsigned)dst) >> 6; int p0 = atomicAdd(&hist[b0], 1);
          if (p0 < CAP) pairs[(size_t)b0 * CAP + p0] = ((dst & 63) << 17) | src;
        }
      }
    }
    return;
  }

  // ---- GEMM role: h[rows b*64..+63] = bf16(x @ W), unscaled ----
  int b = bid - SB;
  unsigned short (*Wt)[136] = (unsigned short (*)[136])smem;
#pragma unroll
  for (int p = 0; p < 16; ++p) {
    int task = p * 256 + t;
    int kg = task >> 7, nn = task & 127;
    float w0 = W[(kg * 4 + 0) * 128 + nn];
    float w1 = W[(kg * 4 + 1) * 128 + nn];
    float w2 = W[(kg * 4 + 2) * 128 + nn];
    float w3 = W[(kg * 4 + 3) * 128 + nn];
    ushort4 u;
    u.x = f2bf(w0); u.y = f2bf(w1); u.z = f2bf(w2); u.w = f2bf(w3);
    *(ushort4*)&Wt[nn][kg * 4] = u;
  }
  __syncthreads();
  int w = t >> 6, lane = t & 63;
  int q = lane >> 4, m = lane & 15;
  int r0 = b * 64 + w * 16;
  f32x4 acc[8];
#pragma unroll
  for (int nt = 0; nt < 8; ++nt) acc[nt] = (f32x4){0.f, 0.f, 0.f, 0.f};
#pragma unroll
  for (int ks = 0; ks < 4; ++ks) {
    int row = r0 + m;
    row = row < n ? row : n - 1;
    const float* xp = x + (size_t)row * 128 + ks * 32 + q * 8;
    float4 a0 = *(const float4*)xp;
    float4 a1 = *(const float4*)(xp + 4);
    short8 af;
    af[0] = (short)f2bf(a0.x); af[1] = (short)f2bf(a0.y);
    af[2] = (short)f2bf(a0.z); af[3] = (short)f2bf(a0.w);
    af[4] = (short)f2bf(a1.x); af[5] = (short)f2bf(a1.y);
    af[6] = (short)f2bf(a1.z); af[7] = (short)f2bf(a1.w);
#pragma unroll
    for (int nt = 0; nt < 8; ++nt) {
      short8 bf = *(const short8*)&Wt[nt * 16 + m][ks * 32 + q * 8];
      acc[nt] = __builtin_amdgcn_mfma_f32_16x16x32_bf16(af, bf, acc[nt], 0, 0, 0);
    }
  }
#pragma unroll
  for (int nt = 0; nt < 8; ++nt)
#pragma unroll
    for (int rg = 0; rg < 4; ++rg) {
      int r = r0 + q * 4 + rg;
      if (r < n) h[(size_t)r * 128 + nt * 16 + m] = f2bf(acc[nt][rg]);
    }
}

// Per-bucket counting sort in LDS -> sorted src list (in place), packed
// (local_off<<16|cnt) per node, dinv per node.
__global__ void __launch_bounds__(256) k_bucket_csr(
    int* __restrict__ pairs, const int* __restrict__ bcursor,
    int* __restrict__ onc, float* __restrict__ dinv, int n) {
  __shared__ int pb[CAP];
  __shared__ int sorted[CAP];
  __shared__ int hist[64], base_[64], cur[64];
  int t = threadIdx.x;
  int b = blockIdx.x;
  int cnt = min(bcursor[b], CAP);
  int* gp = pairs + (size_t)b * CAP;
  for (int i = t; i < cnt; i += 256) pb[i] = gp[i];
  if (t < 64) { hist[t] = 0; cur[t] = 0; }
  __syncthreads();
  for (int i = t; i < cnt; i += 256) atomicAdd(&hist[pb[i] >> 17], 1);
  __syncthreads();
  if (t < 64) {  // wave 0: inclusive scan via shuffles
    int v = hist[t];
    int incl = v;
#pragma unroll
    for (int d = 1; d < 64; d <<= 1) {
      int u = __shfl_up(incl, d, 64);
      if (t >= d) incl += u;
    }
    base_[t] = incl - v;
    int node = b * 64 + t;
    if (node < n) {
      onc[node] = ((incl - v) << 16) | v;
      dinv[node] = rsqrtf((float)v + 1.0f);  // +1 self loop
    }
  }
  __syncthreads();
  for (int i = t; i < cnt; i += 256) {
    int p = pb[i];
    int d = p >> 17;
    int pos = base_[d] + atomicAdd(&cur[d], 1);
    sorted[pos] = p & 0x1FFFF;
  }
  __syncthreads();
  for (int i = t; i < cnt; i += 256) gp[i] = sorted[i];
}

// One wave per node; h is UNSCALED -> multiply each gathered row by
// dinv[src] (wave-uniform broadcast load), final scale dinv[node] + bias.
__global__ void __launch_bounds__(256) k_agg_bias(
    const unsigned int* __restrict__ h2, const float* __restrict__ dinv,
    const int* __restrict__ onc, const int* __restrict__ pairs,
    const float* __restrict__ bias, float* __restrict__ out, int n) {
  int node = blockIdx.x * WPB + (threadIdx.x >> 6);
  int lane = threadIdx.x & 63;
  if (node >= n) return;
  float di = dinv[node];
  unsigned int sp = h2[(size_t)node * 64 + lane];  // self term
  float ax = di * bf_lo(sp), ay = di * bf_hi(sp);
  int v = onc[node];
  int s = (node >> 6) * CAP + (v >> 16);
  int end = s + (v & 0xFFFF);
  const int* __restrict__ csr = pairs;
  for (; s + 8 <= end; s += 8) {
    int i0 = csr[s + 0], i1 = csr[s + 1], i2 = csr[s + 2], i3 = csr[s + 3];
    int i4 = csr[s + 4], i5 = csr[s + 5], i6 = csr[s + 6], i7 = csr[s + 7];
    unsigned int u0 = h2[(size_t)i0 * 64 + lane];
    unsigned int u1 = h2[(size_t)i1 * 64 + lane];
    unsigned int u2 = h2[(size_t)i2 * 64 + lane];
    unsigned int u3 = h2[(size_t)i3 * 64 + lane];
    unsigned int u4 = h2[(size_t)i4 * 64 + lane];
    unsigned int u5 = h2[(size_t)i5 * 64 + lane];
    unsigned int u6 = h2[(size_t)i6 * 64 + lane];
    unsigned int u7 = h2[(size_t)i7 * 64 + lane];
    float d0 = dinv[i0], d1 = dinv[i1], d2 = dinv[i2], d3 = dinv[i3];
    float d4 = dinv[i4], d5 = dinv[i5], d6 = dinv[i6], d7 = dinv[i7];
    ax = fmaf(bf_lo(u0), d0, ax); ay = fmaf(bf_hi(u0), d0, ay);
    ax = fmaf(bf_lo(u1), d1, ax); ay = fmaf(bf_hi(u1), d1, ay);
    ax = fmaf(bf_lo(u2), d2, ax); ay = fmaf(bf_hi(u2), d2, ay);
    ax = fmaf(bf_lo(u3), d3, ax); ay = fmaf(bf_hi(u3), d3, ay);
    ax = fmaf(bf_lo(u4), d4, ax); ay = fmaf(bf_hi(u4), d4, ay);
    ax = fmaf(bf_lo(u5), d5, ax); ay = fmaf(bf_hi(u5), d5, ay);
    ax = fmaf(bf_lo(u6), d6, ax); ay = fmaf(bf_hi(u6), d6, ay);
    ax = fmaf(bf_lo(u7), d7, ax); ay = fmaf(bf_hi(u7), d7, ay);
  }
  for (; s < end; ++s) {
    int i0 = csr[s];
    unsigned int u = h2[(size_t)i0 * 64 + lane];
    float d0 = dinv[i0];
    ax = fmaf(bf_lo(u), d0, ax); ay = fmaf(bf_hi(u), d0, ay);
  }
  float2 bb = ((const float2*)bias)[lane];
  float2 r;
  r.x = fmaf(ax, di, bb.x);
  r.y = fmaf(ay, di, bb.y);
  ((float2*)out)[(size_t)node * 64 + lane] = r;
}

// ======================= round-3 CSR fallback =======================

__global__ void k_init(int* __restrict__ cnt, int n) {
  int i = blockIdx.x * blockDim.x + threadIdx.x;
  if (i < n) cnt[i] = 0;
}

__global__ void k_count4(const int* __restrict__ ei, int* __restrict__ cnt, int E) {
  int i = blockIdx.x * blockDim.x + threadIdx.x;
  int e = i * 4;
  if (e + 3 < E) {
    int4 d = *(const int4*)(ei + E + e);
    atomicAdd(&cnt[d.x], 1); atomicAdd(&cnt[d.y], 1);
    atomicAdd(&cnt[d.z], 1); atomicAdd(&cnt[d.w], 1);
  } else {
    for (; e < E; ++e) atomicAdd(&cnt[ei[E + e]], 1);
  }
}

__global__ void k_scan_local(const int* __restrict__ cnt, int* __restrict__ offs,
                             int* __restrict__ bsums, int n) {
  __shared__ int sh[SCAN_T];
  int t = threadIdx.x;
  int base = blockIdx.x * SCAN_E + t * 4;
  int v0 = 0, v1 = 0, v2 = 0, v3 = 0;
  if (base + 0 < n) v0 = cnt[base + 0];
  if (base + 1 < n) v1 = cnt[base + 1];
  if (base + 2 < n) v2 = cnt[base + 2];
  if (base + 3 < n) v3 = cnt[base + 3];
  int sum = v0 + v1 + v2 + v3;
  sh[t] = sum;
  __syncthreads();
  for (int d = 1; d < SCAN_T; d <<= 1) {
    int xv = (t >= d) ? sh[t - d] : 0;
    __syncthreads();
    sh[t] += xv;
    __syncthreads();
  }
  int run = sh[t] - sum;
  if (base + 0 < n) offs[base + 0] = run; run += v0;
  if (base + 1 < n) offs[base + 1] = run; run += v1;
  if (base + 2 < n) offs[base + 2] = run; run += v2;
  if (base + 3 < n) offs[base + 3] = run;
  if (t == SCAN_T - 1) bsums[blockIdx.x] = sh[t];
}

__global__ void k_scan_bsums(int* __restrict__ bsums, int nb) {
  __shared__ int sh[SCAN_T];
  int t = threadIdx.x;
  int v = (t < nb) ? bsums[t] : 0;
  sh[t] = v;
  __syncthreads();
  for (int d = 1; d < SCAN_T; d <<= 1) {
    int xv = (t >= d) ? sh[t - d] : 0;
    __syncthreads();
    sh[t] += xv;
    __syncthreads();
  }
  if (t < nb) bsums[t] = sh[t] - v;
}

__global__ void k_scan_finish(int* __restrict__ offs, const int* __restrict__ bsums,
                              const int* __restrict__ cnt, int* __restrict__ offs2,
                              float* __restrict__ dinv, int n) {
  int i = blockIdx.x * blockDim.x + threadIdx.x;
  if (i < n) {
    int o = offs[i] + bsums[i / SCAN_E];
    offs[i] = o;
    offs2[i] = o;
    dinv[i] = rsqrtf((float)cnt[i] + 1.0f);
  }
}

__global__ void k_fill4(const int* __restrict__ ei, int* __restrict__ offs2,
                        int* __restrict__ csr, int E) {
  int i = blockIdx.x * blockDim.x + threadIdx.x;
  int e = i * 4;
  if (e + 3 < E) {
    int4 s = *(const int4*)(ei + e);
    int4 d = *(const int4*)(ei + E + e);
    csr[atomicAdd(&offs2[d.x], 1)] = s.x;
    csr[atomicAdd(&offs2[d.y], 1)] = s.y;
    csr[atomicAdd(&offs2[d.z], 1)] = s.z;
    csr[atomicAdd(&offs2[d.w], 1)] = s.w;
  } else {
    for (; e < E; ++e) csr[atomicAdd(&offs2[ei[E + e]], 1)] = ei[e];
  }
}

__global__ void __launch_bounds__(256) k_gemm_h(
    const float* __restrict__ x, const float* __restrict__ W,
    const float* __restrict__ dinv, unsigned short* __restrict__ h, int n) {
  __shared__ alignas(16) unsigned short Wt[128][136];
  int t = threadIdx.x;
#pragma unroll
  for (int p = 0; p < 16; ++p) {
    int task = p * 256 + t;
    int kg = task >> 7, nn = task & 127;
    float w0 = W[(kg * 4 + 0) * 128 + nn];
    float w1 = W[(kg * 4 + 1) * 128 + nn];
    float w2 = W[(kg * 4 + 2) * 128 + nn];
    float w3 = W[(kg * 4 + 3) * 128 + nn];
    ushort4 u;
    u.x = f2bf(w0); u.y = f2bf(w1); u.z = f2bf(w2); u.w = f2bf(w3);
    *(ushort4*)&Wt[nn][kg * 4] = u;
  }
  __syncthreads();
  int w = t >> 6, lane = t & 63;
  int q = lane >> 4, m = lane & 15;
  int r0 = blockIdx.x * 64 + w * 16;
  f32x4 acc[8];
#pragma unroll
  for (int nt = 0; nt < 8; ++nt) acc[nt] = (f32x4){0.f, 0.f, 0.f, 0.f};
  float dscale[4];
#pragma unroll
  for (int rg = 0; rg < 4; ++rg) {
    int r = r0 + q * 4 + rg;
    dscale[rg] = dinv[r < n ? r : n - 1];
  }
#pragma unroll
  for (int ks = 0; ks < 4; ++ks) {
    int row = r0 + m;
    row = row < n ? row : n - 1;
    const float* xp = x + (size_t)row * 128 + ks * 32 + q * 8;
    float4 a0 = *(const float4*)xp;
    float4 a1 = *(const float4*)(xp + 4);
    short8 af;
    af[0] = (short)f2bf(a0.x); af[1] = (short)f2bf(a0.y);
    af[2] = (short)f2bf(a0.z); af[3] = (short)f2bf(a0.w);
    af[4] = (short)f2bf(a1.x); af[5] = (short)f2bf(a1.y);
    af[6] = (short)f2bf(a1.z); af[7] = (short)f2bf(a1.w);
#pragma unroll
    for (int nt = 0; nt < 8; ++nt) {
      short8 bf = *(const short8*)&Wt[nt * 16 + m][ks * 32 + q * 8];
      acc[nt] = __builtin_amdgcn_mfma_f32_16x16x32_bf16(af, bf, acc[nt], 0, 0, 0);
    }
  }
#pragma unroll
  for (int nt = 0; nt < 8; ++nt)
#pragma unroll
    for (int rg = 0; rg < 4; ++rg) {
      int r = r0 + q * 4 + rg;
      if (r < n) h[(size_t)r * 128 + nt * 16 + m] = f2bf(acc[nt][rg] * dscale[rg]);
    }
}

__global__ void __launch_bounds__(256) k_agg_bias_csr(
    const unsigned int* __restrict__ h2, const float* __restrict__ dinv,
    const int* __restrict__ offs, const int* __restrict__ cnt,
    const int* __restrict__ csr, const float* __restrict__ bias,
    float* __restrict__ out, int n) {
  int node = blockIdx.x * WPB + (threadIdx.x >> 6);
  int lane = threadIdx.x & 63;
  if (node >= n) return;
  unsigned int sp = h2[(size_t)node * 64 + lane];
  float ax = bf_lo(sp), ay = bf_hi(sp);
  int s = offs[node];
  int end = s + cnt[node];
  for (; s + 8 <= end; s += 8) {
    int i0 = csr[s + 0], i1 = csr[s + 1], i2 = csr[s + 2], i3 = csr[s + 3];
    int i4 = csr[s + 4], i5 = csr[s + 5], i6 = csr[s + 6], i7 = csr[s + 7];
    unsigned int u0 = h2[(size_t)i0 * 64 + lane];
    unsigned int u1 = h2[(size_t)i1 * 64 + lane];
    unsigned int u2 = h2[(size_t)i2 * 64 + lane];
    unsigned int u3 = h2[(size_t)i3 * 64 + lane];
    unsigned int u4 = h2[(size_t)i4 * 64 + lane];
    unsigned int u5 = h2[(size_t)i5 * 64 + lane];
    unsigned int u6 = h2[(size_t)i6 * 64 + lane];
    unsigned int u7 = h2[(size_t)i7 * 64 + lane];
    ax += (bf_lo(u0) + bf_lo(u1)) + (bf_lo(u2) + bf_lo(u3)) +
          (bf_lo(u4) + bf_lo(u5)) + (bf_lo(u6) + bf_lo(u7));
    ay += (bf_hi(u0) + bf_hi(u1)) + (bf_hi(u2) + bf_hi(u3)) +
          (bf_hi(u4) + bf_hi(u5)) + (bf_hi(u6) + bf_hi(u7));
  }
  for (; s < end; ++s) {
    unsigned int u = h2[(size_t)csr[s] * 64 + lane];
    ax += bf_lo(u); ay += bf_hi(u);
  }
  float di = dinv[node];
  float2 bb = ((const float2*)bias)[lane];
  float2 r;
  r.x = fmaf(ax, di, bb.x);
  r.y = fmaf(ay, di, bb.y);
  ((float2*)out)[(size_t)node * 64 + lane] = r;
}

extern "C" void kernel_launch(void* const* d_in, const int* in_sizes, int n_in,
                              void* d_out, int out_size, void* d_ws, size_t ws_size,
                              hipStream_t stream) {
  const float* x = (const float*)d_in[0];
  const int* ei = (const int*)d_in[1];   // harness delivers integers as int32
  const float* Wm = (const float*)d_in[2];
  const float* bias = (const float*)d_in[3];
  float* out = (float*)d_out;

  int N = in_sizes[0] / 128;
  int E = in_sizes[1] / 2;
  int NB = (N + 63) >> 6;
  int SB = (E + SC_T - 1) / SC_T;

  size_t need_new = (size_t)N * 8 + 8192 + (size_t)NB * CAP * 4 + (size_t)N * 256;

  if (ws_size >= need_new && N <= (1 << 17) && NB <= 2048) {
    char* p = (char*)d_ws;
    float* dinv = (float*)p;       p += (size_t)N * 4;
    int* onc = (int*)p;            p += (size_t)N * 4;
    int* bcursor = (int*)p;        p += 8192;
    int* pairs = (int*)p;          p += (size_t)NB * CAP * 4;
    unsigned short* h = (unsigned short*)p;

    k_zero<<<(NB + 255) / 256, 256, 0, stream>>>(bcursor, NB);
    k_scatter_gemm<<<SB + NB, 256, 0, stream>>>(ei, bcursor, pairs, E, NB, SB,
                                                x, Wm, h, N);
    k_bucket_csr<<<NB, 256, 0, stream>>>(pairs, bcursor, onc, dinv, N);
    k_agg_bias<<<(N + WPB - 1) / WPB, 256, 0, stream>>>(
        (const unsigned int*)h, dinv, onc, pairs, bias, out, N);
    return;
  }

  // ---- round-3 CSR fallback ----
  char* p = (char*)d_ws;
  int* cnt = (int*)p;        p += (size_t)N * 4;
  int* offs = (int*)p;       p += (size_t)N * 4;
  int* offs2 = (int*)p;      p += (size_t)N * 4;
  float* dinv = (float*)p;   p += (size_t)N * 4;
  int* bsums = (int*)p;      p += 1024;
  int* csr = (int*)p;        p += (size_t)E * 4;
  unsigned short* h = (unsigned short*)p;

  int nb_n = (N + 255) / 256;
  int nb_e4 = ((E + 3) / 4 + 255) / 256;
  int nb_scan = (N + SCAN_E - 1) / SCAN_E;

  k_init<<<nb_n, 256, 0, stream>>>(cnt, N);
  k_count4<<<nb_e4, 256, 0, stream>>>(ei, cnt, E);
  k_scan_local<<<nb_scan, SCAN_T, 0, stream>>>(cnt, offs, bsums, N);
  k_scan_bsums<<<1, SCAN_T, 0, stream>>>(bsums, nb_scan);
  k_scan_finish<<<nb_n, 256, 0, stream>>>(offs, bsums, cnt, offs2, dinv, N);
  k_fill4<<<nb_e4, 256, 0, stream>>>(ei, offs2, csr, E);
  k_gemm_h<<<(N + 63) / 64, 256, 0, stream>>>(x, Wm, dinv, h, N);
  k_agg_bias_csr<<<(N + WPB - 1) / WPB, 256, 0, stream>>>(
      (const unsigned int*)h, dinv, offs, cnt, csr, bias, out, N);
}